// Round 5
// baseline (121.145 us; speedup 1.0000x reference)
//
#include <hip/hip_runtime.h>
#include <hip/hip_bf16.h>
#include <cstdint>

#define HEADS 12

typedef __attribute__((ext_vector_type(8))) __bf16 bf16x8;
typedef __attribute__((ext_vector_type(4))) __bf16 bf16x4;
typedef __attribute__((ext_vector_type(4))) float f32x4;

#define AS1 __attribute__((address_space(1)))
#define AS3 __attribute__((address_space(3)))

__device__ __forceinline__ void gload16(const void* src, void* lds) {
  __builtin_amdgcn_global_load_lds((AS1 void*)src, (AS3 void*)lds, 16, 0, 0);
}

__device__ __forceinline__ uint32_t cvtpk(float lo, float hi) {
  uint32_t r;
  asm("v_cvt_pk_bf16_f32 %0, %1, %2" : "=v"(r) : "v"(lo), "v"(hi));
  return r;
}

__device__ __forceinline__ float exp2_fast(float x) {
  float r;
  asm("v_exp_f32 %0, %1" : "=v"(r) : "v"(x));
  return r;
}

// ---------------- cast fp32 -> bf16: x (6291456) then r (3145728) ----------------
__global__ void k_cast2(const float* __restrict__ x, const float* __restrict__ r,
                        __bf16* __restrict__ xb, __bf16* __restrict__ rb) {
  int i = (blockIdx.x * 256 + threadIdx.x) * 4;
  const float* src;
  __bf16* dst;
  int off;
  if (i < 6291456) { src = x; dst = xb; off = i; }
  else             { src = r; dst = rb; off = i - 6291456; }
  float4 v = *(const float4*)(src + off);
  bf16x4 o;
  o[0] = (__bf16)v.x; o[1] = (__bf16)v.y; o[2] = (__bf16)v.z; o[3] = (__bf16)v.w;
  *(bf16x4*)(dst + off) = o;
}

// ------------- transpose+cast all 3 weights: W[K][N] f32 -> Wt[N][K] bf16 (×scale) -------------
__global__ void k_twc3(const float* __restrict__ Wq, const float* __restrict__ Wkv,
                       const float* __restrict__ Wp, __bf16* __restrict__ wqt,
                       __bf16* __restrict__ wkvt, __bf16* __restrict__ wpt) {
  __shared__ float tile[32][33];
  const float* W; __bf16* Wt; int N; float scale;
  if (blockIdx.z == 0)      { W = Wq;  Wt = wqt;  N = 768;  scale = 0.18033688011112042f; }
  else if (blockIdx.z == 1) { W = Wkv; Wt = wkvt; N = 1536; scale = 1.0f; }
  else                      { W = Wp;  Wt = wpt;  N = 768;  scale = 1.0f; }
  int nt = blockIdx.x, kt = blockIdx.y;
  if (nt * 32 >= N) return;
  int c = threadIdx.x & 31, r0 = threadIdx.x >> 5;
#pragma unroll
  for (int i = 0; i < 4; ++i) {
    int r = r0 + i * 8;
    tile[r][c] = W[(size_t)(kt * 32 + r) * N + nt * 32 + c];
  }
  __syncthreads();
#pragma unroll
  for (int i = 0; i < 4; ++i) {
    int r = r0 + i * 8;
    Wt[(size_t)(nt * 32 + r) * 768 + kt * 32 + c] = (__bf16)(tile[c][r] * scale);
  }
}

// ---------------- bf16 GEMM: C[M][N] = A[M][K] * Bt[N][K]^T ----------------
// 128x128 tile, BK=64, 4 waves. XCD-aware swizzle. Optional transposed-V side-write:
// if vTp != null, columns >= 768 are written ONLY to vTp[b*768 + (col-768)][row%1024].
template<bool BF16OUT>
__global__ __launch_bounds__(256, 2) void k_gemm(
    const __bf16* __restrict__ A, const __bf16* __restrict__ Bt,
    void* __restrict__ C, const float* __restrict__ bias, __bf16* __restrict__ vTp,
    int M, int N, int K) {
  __shared__ __align__(16) char ldsA[2][16384];
  __shared__ __align__(16) char ldsB[2][16384];
  const int tid = threadIdx.x;
  const int ln = tid & 63;
  const int w = tid >> 6;
  const int nwx = gridDim.x;
  int bid = blockIdx.y * nwx + blockIdx.x;
  const int cpx = (nwx * gridDim.y) >> 3;
  bid = (bid & 7) * cpx + (bid >> 3);
  const int bm0 = (bid / nwx) * 128, bn0 = (bid % nwx) * 128;
  const int wm0 = (w >> 1) * 64, wn0 = (w & 1) * 64;

  auto stage = [&](char* lds, const __bf16* G, int row0, int k0) {
    const char* gb = (const char*)(G + (size_t)row0 * K + k0);
#pragma unroll
    for (int c = 0; c < 4; ++c) {
      int off = c * 4096 + tid * 16;
      int row = off >> 7;
      int s = ((off >> 4) & 7) ^ (row & 7);
      gload16(gb + (size_t)row * (K * 2) + (s << 4), lds + c * 4096 + (w << 10));
    }
  };

  f32x4 acc[4][4] = {};
  const int NK = K >> 6;
  stage(ldsA[0], A, bm0, 0);
  stage(ldsB[0], Bt, bn0, 0);
  __syncthreads();
  for (int kt = 0; kt < NK; ++kt) {
    const char* bufA = ldsA[kt & 1];
    const char* bufB = ldsB[kt & 1];
    if (kt + 1 < NK) {
      stage(ldsA[(kt + 1) & 1], A, bm0, (kt + 1) << 6);
      stage(ldsB[(kt + 1) & 1], Bt, bn0, (kt + 1) << 6);
    }
    bf16x8 af[2][4], bf[2][4];
#pragma unroll
    for (int kk = 0; kk < 2; ++kk)
#pragma unroll
      for (int mt = 0; mt < 4; ++mt) {
        int row = wm0 + mt * 16 + (ln & 15);
        af[kk][mt] = *(const bf16x8*)(bufA + row * 128 + (((kk * 4 + (ln >> 4)) ^ (row & 7)) << 4));
      }
#pragma unroll
    for (int kk = 0; kk < 2; ++kk)
#pragma unroll
      for (int nt = 0; nt < 4; ++nt) {
        int row = wn0 + nt * 16 + (ln & 15);
        bf[kk][nt] = *(const bf16x8*)(bufB + row * 128 + (((kk * 4 + (ln >> 4)) ^ (row & 7)) << 4));
      }
    __builtin_amdgcn_s_setprio(1);
#pragma unroll
    for (int kk = 0; kk < 2; ++kk)
#pragma unroll
      for (int mt = 0; mt < 4; ++mt)
#pragma unroll
        for (int nt = 0; nt < 4; ++nt)
          acc[mt][nt] = __builtin_amdgcn_mfma_f32_16x16x32_bf16(af[kk][mt], bf[kk][nt], acc[mt][nt], 0, 0, 0);
    __builtin_amdgcn_s_setprio(0);
    __syncthreads();
  }
#pragma unroll
  for (int mt = 0; mt < 4; ++mt) {
    int row = bm0 + wm0 + mt * 16 + ((ln >> 4) << 2);
#pragma unroll
    for (int nt = 0; nt < 4; ++nt) {
      int col = bn0 + wn0 + nt * 16 + (ln & 15);
      if (BF16OUT) {
        if (vTp != nullptr && bn0 >= 768) {
          // V part: write transposed into vT[b*768 + (col-768)][row & 1023]
          bf16x4 o;
#pragma unroll
          for (int jj = 0; jj < 4; ++jj) o[jj] = (__bf16)acc[mt][nt][jj];
          *(bf16x4*)(vTp + ((size_t)((row >> 10) * 768 + col - 768)) * 1024 + (row & 1023)) = o;
        } else {
          __bf16* Cb = (__bf16*)C;
#pragma unroll
          for (int jj = 0; jj < 4; ++jj)
            Cb[(size_t)(row + jj) * N + col] = (__bf16)acc[mt][nt][jj];
        }
      } else {
        float* Cf = (float*)C;
        float bv = bias[col];
#pragma unroll
        for (int jj = 0; jj < 4; ++jj)
          Cf[(size_t)(row + jj) * N + col] = acc[mt][nt][jj] + bv;
      }
    }
  }
}

// ---------------- flash attention: 8 waves x 32 q rows (m=2), 3-deep pipeline ----------------
// block = 512 thr, 256 q rows. KVBLK=64, 16 tiles. K/V frag reads shared across both
// m sub-tiles -> half the LDS traffic per q-row vs 16q/wave. Q pre-scaled by
// SCALE*log2e. exp2-domain online softmax with defer-max; lane-partial lrow;
// P^T via cvt_pk+permlane; O^T = mfma(V^T,P^T). Counted vmcnt(2) per tile.
__global__ __launch_bounds__(512, 4) void k_attn(
    const __bf16* __restrict__ q, const __bf16* __restrict__ kv,
    const __bf16* __restrict__ vT, __bf16* __restrict__ ao) {
  __shared__ __align__(16) char ldsK[3][8192];
  __shared__ __align__(16) char ldsV[3][8192];
  const int tid = threadIdx.x, ln = tid & 63, w = tid >> 6, g = ln >> 4;
  const int qt = blockIdx.x, bh = blockIdx.y;
  const int b = bh / HEADS, h = bh % HEADS;
  const int qbase = b * 2048 + qt * 256 + w * 32;

  const char* kgb = (const char*)(kv + ((size_t)b * 1024) * 1536 + h * 64);
  const char* vgb = (const char*)(vT + ((size_t)(b * 768 + h * 64)) * 1024);

  const int srow = tid >> 3;                        // 0..63
  const int scol = (((tid & 7) ^ (srow & 7)) << 4); // swizzled byte col
  const int ldst = w * 1024;                        // wave-uniform LDS base

  auto stageKV = [&](int t, int buf) {
    gload16(kgb + (size_t)(t * 64 + srow) * 3072 + scol, ldsK[buf] + ldst);
    gload16(vgb + (size_t)srow * 2048 + (size_t)t * 128 + scol, ldsV[buf] + ldst);
  };

  // Q fragments direct to registers (pre-scaled by SCALE*log2e)
  bf16x8 qf[2][2];
#pragma unroll
  for (int m = 0; m < 2; ++m)
#pragma unroll
    for (int kk = 0; kk < 2; ++kk)
      qf[m][kk] = *(const bf16x8*)(q + (size_t)(qbase + m * 16 + (ln & 15)) * 768 + h * 64 + (kk * 4 + g) * 8);

  stageKV(0, 0);
  stageKV(1, 1);

  f32x4 acc[2][4] = {};
  float mrow[2] = {-1e30f, -1e30f};
  float lrow[2] = {0.f, 0.f};

  asm volatile("s_waitcnt vmcnt(2)" ::: "memory");  // stage(0) landed
  __builtin_amdgcn_s_barrier();

  for (int t = 0; t < 16; ++t) {
    if (t < 14) stageKV(t + 2, (t + 2) % 3);
    const char* bufK = ldsK[t % 3];
    const char* bufV = ldsV[t % 3];

    // S^T = K . Q^T  (K-frags shared by both m)
    f32x4 sf[2][4] = {};
    __builtin_amdgcn_s_setprio(1);
#pragma unroll
    for (int kk = 0; kk < 2; ++kk)
#pragma unroll
      for (int nt = 0; nt < 4; ++nt) {
        int row = nt * 16 + (ln & 15);
        bf16x8 kf = *(const bf16x8*)(bufK + row * 128 + (((kk * 4 + g) ^ (row & 7)) << 4));
        sf[0][nt] = __builtin_amdgcn_mfma_f32_16x16x32_bf16(kf, qf[0][kk], sf[0][nt], 0, 0, 0);
        sf[1][nt] = __builtin_amdgcn_mfma_f32_16x16x32_bf16(kf, qf[1][kk], sf[1][nt], 0, 0, 0);
      }
    __builtin_amdgcn_s_setprio(0);

    // online softmax (exp2 domain); lane owns q=(ln&15), kv slice {16nt+4g+jj}
    bf16x8 pb[2][2];
#pragma unroll
    for (int m = 0; m < 2; ++m) {
      float lm = sf[m][0][0];
#pragma unroll
      for (int nt = 0; nt < 4; ++nt)
#pragma unroll
        for (int jj = 0; jj < 4; ++jj) lm = fmaxf(lm, sf[m][nt][jj]);
      if (!__all(lm <= mrow[m] + 8.0f)) {
        float mx = lm;
        mx = fmaxf(mx, __shfl_xor(mx, 16, 64));
        mx = fmaxf(mx, __shfl_xor(mx, 32, 64));
        float mn = fmaxf(mrow[m], mx);
        float corr = exp2_fast(mrow[m] - mn);
        mrow[m] = mn;
        lrow[m] *= corr;
#pragma unroll
        for (int dt = 0; dt < 4; ++dt) acc[m][dt] *= corr;
      }
      float p[4][4];
      f32x4 ps = {0.f, 0.f, 0.f, 0.f};
#pragma unroll
      for (int nt = 0; nt < 4; ++nt)
#pragma unroll
        for (int jj = 0; jj < 4; ++jj) {
          float e = exp2_fast(sf[m][nt][jj] - mrow[m]);
          p[nt][jj] = e;
          ps[jj] += e;
        }
      lrow[m] += (ps[0] + ps[1]) + (ps[2] + ps[3]);

      // P^T fragments: cvt_pk + permlane32/16 swap cascade
      uint32_t c0[4], c1[4];
#pragma unroll
      for (int nt = 0; nt < 4; ++nt) {
        c0[nt] = cvtpk(p[nt][0], p[nt][1]);
        c1[nt] = cvtpk(p[nt][2], p[nt][3]);
      }
#pragma unroll
      for (int kk = 0; kk < 2; ++kk) {
        uint32_t x0 = c0[2 * kk], y0 = c0[2 * kk + 1];
        asm("v_permlane32_swap_b32 %0, %1" : "+v"(x0), "+v"(y0));
        asm("v_permlane16_swap_b32 %0, %1" : "+v"(x0), "+v"(y0));
        uint32_t x1 = c1[2 * kk], y1 = c1[2 * kk + 1];
        asm("v_permlane32_swap_b32 %0, %1" : "+v"(x1), "+v"(y1));
        asm("v_permlane16_swap_b32 %0, %1" : "+v"(x1), "+v"(y1));
        union { uint32_t u[4]; bf16x8 v; } pk;
        pk.u[0] = x0; pk.u[1] = x1; pk.u[2] = y0; pk.u[3] = y1;
        pb[m][kk] = pk.v;
      }
    }

    // O^T += V^T . P^T  (V-frags shared by both m)
    __builtin_amdgcn_s_setprio(1);
#pragma unroll
    for (int kk = 0; kk < 2; ++kk)
#pragma unroll
      for (int dt = 0; dt < 4; ++dt) {
        int row = dt * 16 + (ln & 15);
        bf16x8 vf = *(const bf16x8*)(bufV + row * 128 + (((kk * 4 + g) ^ (row & 7)) << 4));
        acc[0][dt] = __builtin_amdgcn_mfma_f32_16x16x32_bf16(vf, pb[0][kk], acc[0][dt], 0, 0, 0);
        acc[1][dt] = __builtin_amdgcn_mfma_f32_16x16x32_bf16(vf, pb[1][kk], acc[1][dt], 0, 0, 0);
      }
    __builtin_amdgcn_s_setprio(0);

    if (t < 14) {
      asm volatile("s_waitcnt vmcnt(2)" ::: "memory");  // t+1 landed, t+2 in flight
      __builtin_amdgcn_s_barrier();
    } else if (t == 14) {
      asm volatile("s_waitcnt vmcnt(0)" ::: "memory");
      __builtin_amdgcn_s_barrier();
    }
  }

  // epilogue: reduce lane-partial lrow across the 4 kv groups, write O
#pragma unroll
  for (int m = 0; m < 2; ++m) {
    float l = lrow[m];
    l += __shfl_xor(l, 16, 64);
    l += __shfl_xor(l, 32, 64);
    float inv = 1.0f / l;
    size_t rowb = (size_t)(qbase + m * 16 + (ln & 15)) * 768 + h * 64;
#pragma unroll
    for (int dt = 0; dt < 4; ++dt) {
      bf16x4 o;
#pragma unroll
      for (int jj = 0; jj < 4; ++jj) o[jj] = (__bf16)(acc[m][dt][jj] * inv);
      *(bf16x4*)(ao + rowb + 16 * dt + 4 * g) = o;
    }
  }
}

extern "C" void kernel_launch(void* const* d_in, const int* in_sizes, int n_in,
                              void* d_out, int out_size, void* d_ws, size_t ws_size,
                              hipStream_t stream) {
  const float* x = (const float*)d_in[0];
  const float* r = (const float*)d_in[1];
  const float* Wq = (const float*)d_in[2];
  const float* Wkv = (const float*)d_in[3];
  const float* Wp = (const float*)d_in[4];
  const float* bp = (const float*)d_in[5];

  char* ws = (char*)d_ws;
  __bf16* xb  = (__bf16*)ws; ws += (size_t)6291456 * 2;  // x bf16 (8192x768)
  __bf16* rb  = (__bf16*)ws; ws += (size_t)3145728 * 2;  // r bf16 (4096x768)
  __bf16* wqt = (__bf16*)ws; ws += (size_t)589824 * 2;   // W_q^T * SCALE*log2e
  __bf16* wkvt= (__bf16*)ws; ws += (size_t)1179648 * 2;  // W_kv^T (1536x768)
  __bf16* wpt = (__bf16*)ws; ws += (size_t)589824 * 2;   // W_proj^T (768x768)
  __bf16* qb  = (__bf16*)ws; ws += (size_t)6291456 * 2;  // q (8192x768), pre-scaled
  __bf16* kvb = (__bf16*)ws; ws += (size_t)6291456 * 2;  // kv (K half valid)
  __bf16* vT  = (__bf16*)ws; ws += (size_t)3145728 * 2;  // v^T (4 x 768 x 1024)
  __bf16* ao  = (__bf16*)ws;                              // attn out (8192x768)

  k_cast2<<<9216, 256, 0, stream>>>(x, r, xb, rb);
  k_twc3<<<dim3(48, 24, 3), 256, 0, stream>>>(Wq, Wkv, Wp, wqt, wkvt, wpt);
  k_gemm<true><<<dim3(6, 64), 256, 0, stream>>>(xb, wqt, qb, nullptr, nullptr, 8192, 768, 768);
  k_gemm<true><<<dim3(12, 32), 256, 0, stream>>>(rb, wkvt, kvb, nullptr, vT, 4096, 1536, 768);
  k_attn<<<dim3(8, 48), 512, 0, stream>>>(qb, kvb, vT, ao);
  k_gemm<false><<<dim3(6, 64), 256, 0, stream>>>(ao, wpt, d_out, bp, nullptr, 8192, 768, 768);
}

// Round 6
// 102.360 us; speedup vs baseline: 1.1835x; 1.1835x over previous
//
#include <hip/hip_runtime.h>
#include <hip/hip_bf16.h>
#include <cstdint>

#define HEADS 12

typedef __attribute__((ext_vector_type(8))) __bf16 bf16x8;
typedef __attribute__((ext_vector_type(4))) __bf16 bf16x4;
typedef __attribute__((ext_vector_type(4))) float f32x4;
typedef __attribute__((ext_vector_type(16))) float f32x16;

#define AS1 __attribute__((address_space(1)))
#define AS3 __attribute__((address_space(3)))

__device__ __forceinline__ void gload16(const void* src, void* lds) {
  __builtin_amdgcn_global_load_lds((AS1 void*)src, (AS3 void*)lds, 16, 0, 0);
}

__device__ __forceinline__ uint32_t cvtpk(float lo, float hi) {
  uint32_t r;
  asm("v_cvt_pk_bf16_f32 %0, %1, %2" : "=v"(r) : "v"(lo), "v"(hi));
  return r;
}

__device__ __forceinline__ float exp2_fast(float x) {
  float r;
  asm("v_exp_f32 %0, %1" : "=v"(r) : "v"(x));
  return r;
}

// ---------------- cast fp32 -> bf16: x (6291456) then r (3145728) ----------------
__global__ void k_cast2(const float* __restrict__ x, const float* __restrict__ r,
                        __bf16* __restrict__ xb, __bf16* __restrict__ rb) {
  int i = (blockIdx.x * 256 + threadIdx.x) * 4;
  const float* src;
  __bf16* dst;
  int off;
  if (i < 6291456) { src = x; dst = xb; off = i; }
  else             { src = r; dst = rb; off = i - 6291456; }
  float4 v = *(const float4*)(src + off);
  bf16x4 o;
  o[0] = (__bf16)v.x; o[1] = (__bf16)v.y; o[2] = (__bf16)v.z; o[3] = (__bf16)v.w;
  *(bf16x4*)(dst + off) = o;
}

// ------------- transpose+cast all 3 weights: W[K][N] f32 -> Wt[N][K] bf16 (×scale) -------------
__global__ void k_twc3(const float* __restrict__ Wq, const float* __restrict__ Wkv,
                       const float* __restrict__ Wp, __bf16* __restrict__ wqt,
                       __bf16* __restrict__ wkvt, __bf16* __restrict__ wpt) {
  __shared__ float tile[32][33];
  const float* W; __bf16* Wt; int N; float scale;
  if (blockIdx.z == 0)      { W = Wq;  Wt = wqt;  N = 768;  scale = 0.18033688011112042f; }
  else if (blockIdx.z == 1) { W = Wkv; Wt = wkvt; N = 1536; scale = 1.0f; }
  else                      { W = Wp;  Wt = wpt;  N = 768;  scale = 1.0f; }
  int nt = blockIdx.x, kt = blockIdx.y;
  if (nt * 32 >= N) return;
  int c = threadIdx.x & 31, r0 = threadIdx.x >> 5;
#pragma unroll
  for (int i = 0; i < 4; ++i) {
    int r = r0 + i * 8;
    tile[r][c] = W[(size_t)(kt * 32 + r) * N + nt * 32 + c];
  }
  __syncthreads();
#pragma unroll
  for (int i = 0; i < 4; ++i) {
    int r = r0 + i * 8;
    Wt[(size_t)(nt * 32 + r) * 768 + kt * 32 + c] = (__bf16)(tile[c][r] * scale);
  }
}

// ---------------- fused Q-proj + KV-proj GEMM (768 blocks, flat id) ----------------
// id<384: qb[8192x768] = xb @ wqt^T ; else kvb/vT = rb @ wkvt^T (V side-written transposed)
__global__ __launch_bounds__(256, 2) void k_gemm12(
    const __bf16* __restrict__ xb, const __bf16* __restrict__ rb,
    const __bf16* __restrict__ wqt, const __bf16* __restrict__ wkvt,
    __bf16* __restrict__ qb, __bf16* __restrict__ kvb, __bf16* __restrict__ vTp) {
  __shared__ __align__(16) char ldsA[2][16384];
  __shared__ __align__(16) char ldsB[2][16384];
  const int tid = threadIdx.x;
  const int ln = tid & 63;
  const int w = tid >> 6;
  int id = blockIdx.x;
  id = (id & 7) * 96 + (id >> 3);  // XCD chunking (768 % 8 == 0)
  const __bf16* A; const __bf16* Bt; __bf16* C; int N, bm0, bn0; bool qpart;
  if (id < 384) { A = xb; Bt = wqt;  C = qb;  N = 768;  bm0 = (id / 6) * 128;  bn0 = (id % 6) * 128;  qpart = true; }
  else { int i2 = id - 384; A = rb; Bt = wkvt; C = kvb; N = 1536; bm0 = (i2 / 12) * 128; bn0 = (i2 % 12) * 128; qpart = false; }
  const int wm0 = (w >> 1) * 64, wn0 = (w & 1) * 64;

  auto stage = [&](char* lds, const __bf16* G, int row0, int k0) {
    const char* gb = (const char*)(G + (size_t)row0 * 768 + k0);
#pragma unroll
    for (int c = 0; c < 4; ++c) {
      int off = c * 4096 + tid * 16;
      int row = off >> 7;
      int s = ((off >> 4) & 7) ^ (row & 7);
      gload16(gb + (size_t)row * 1536 + (s << 4), lds + c * 4096 + (w << 10));
    }
  };

  f32x4 acc[4][4] = {};
  stage(ldsA[0], A, bm0, 0);
  stage(ldsB[0], Bt, bn0, 0);
  __syncthreads();
  for (int kt = 0; kt < 12; ++kt) {
    const char* bufA = ldsA[kt & 1];
    const char* bufB = ldsB[kt & 1];
    if (kt + 1 < 12) {
      stage(ldsA[(kt + 1) & 1], A, bm0, (kt + 1) << 6);
      stage(ldsB[(kt + 1) & 1], Bt, bn0, (kt + 1) << 6);
    }
    bf16x8 af[2][4], bf[2][4];
#pragma unroll
    for (int kk = 0; kk < 2; ++kk)
#pragma unroll
      for (int mt = 0; mt < 4; ++mt) {
        int row = wm0 + mt * 16 + (ln & 15);
        af[kk][mt] = *(const bf16x8*)(bufA + row * 128 + (((kk * 4 + (ln >> 4)) ^ (row & 7)) << 4));
      }
#pragma unroll
    for (int kk = 0; kk < 2; ++kk)
#pragma unroll
      for (int nt = 0; nt < 4; ++nt) {
        int row = wn0 + nt * 16 + (ln & 15);
        bf[kk][nt] = *(const bf16x8*)(bufB + row * 128 + (((kk * 4 + (ln >> 4)) ^ (row & 7)) << 4));
      }
    __builtin_amdgcn_s_setprio(1);
#pragma unroll
    for (int kk = 0; kk < 2; ++kk)
#pragma unroll
      for (int mt = 0; mt < 4; ++mt)
#pragma unroll
        for (int nt = 0; nt < 4; ++nt)
          acc[mt][nt] = __builtin_amdgcn_mfma_f32_16x16x32_bf16(af[kk][mt], bf[kk][nt], acc[mt][nt], 0, 0, 0);
    __builtin_amdgcn_s_setprio(0);
    __syncthreads();
  }
#pragma unroll
  for (int mt = 0; mt < 4; ++mt) {
    int row = bm0 + wm0 + mt * 16 + ((ln >> 4) << 2);
#pragma unroll
    for (int nt = 0; nt < 4; ++nt) {
      int col = bn0 + wn0 + nt * 16 + (ln & 15);
      if (!qpart && bn0 >= 768) {
        bf16x4 o;
#pragma unroll
        for (int jj = 0; jj < 4; ++jj) o[jj] = (__bf16)acc[mt][nt][jj];
        *(bf16x4*)(vTp + ((size_t)((row >> 10) * 768 + col - 768)) * 1024 + (row & 1023)) = o;
      } else {
#pragma unroll
        for (int jj = 0; jj < 4; ++jj)
          C[(size_t)(row + jj) * N + col] = (__bf16)acc[mt][nt][jj];
      }
    }
  }
}

// ---------------- out-proj GEMM: C[M][N] f32 = A @ Bt^T + bias ----------------
__global__ __launch_bounds__(256, 2) void k_gemmP(
    const __bf16* __restrict__ A, const __bf16* __restrict__ Bt,
    float* __restrict__ C, const float* __restrict__ bias) {
  __shared__ __align__(16) char ldsA[2][16384];
  __shared__ __align__(16) char ldsB[2][16384];
  const int tid = threadIdx.x;
  const int ln = tid & 63;
  const int w = tid >> 6;
  int bid = blockIdx.y * 6 + blockIdx.x;
  bid = (bid & 7) * 48 + (bid >> 3);  // 384 % 8 == 0
  const int bm0 = (bid / 6) * 128, bn0 = (bid % 6) * 128;
  const int wm0 = (w >> 1) * 64, wn0 = (w & 1) * 64;

  auto stage = [&](char* lds, const __bf16* G, int row0, int k0) {
    const char* gb = (const char*)(G + (size_t)row0 * 768 + k0);
#pragma unroll
    for (int c = 0; c < 4; ++c) {
      int off = c * 4096 + tid * 16;
      int row = off >> 7;
      int s = ((off >> 4) & 7) ^ (row & 7);
      gload16(gb + (size_t)row * 1536 + (s << 4), lds + c * 4096 + (w << 10));
    }
  };

  f32x4 acc[4][4] = {};
  stage(ldsA[0], A, bm0, 0);
  stage(ldsB[0], Bt, bn0, 0);
  __syncthreads();
  for (int kt = 0; kt < 12; ++kt) {
    const char* bufA = ldsA[kt & 1];
    const char* bufB = ldsB[kt & 1];
    if (kt + 1 < 12) {
      stage(ldsA[(kt + 1) & 1], A, bm0, (kt + 1) << 6);
      stage(ldsB[(kt + 1) & 1], Bt, bn0, (kt + 1) << 6);
    }
    bf16x8 af[2][4], bf[2][4];
#pragma unroll
    for (int kk = 0; kk < 2; ++kk)
#pragma unroll
      for (int mt = 0; mt < 4; ++mt) {
        int row = wm0 + mt * 16 + (ln & 15);
        af[kk][mt] = *(const bf16x8*)(bufA + row * 128 + (((kk * 4 + (ln >> 4)) ^ (row & 7)) << 4));
      }
#pragma unroll
    for (int kk = 0; kk < 2; ++kk)
#pragma unroll
      for (int nt = 0; nt < 4; ++nt) {
        int row = wn0 + nt * 16 + (ln & 15);
        bf[kk][nt] = *(const bf16x8*)(bufB + row * 128 + (((kk * 4 + (ln >> 4)) ^ (row & 7)) << 4));
      }
    __builtin_amdgcn_s_setprio(1);
#pragma unroll
    for (int kk = 0; kk < 2; ++kk)
#pragma unroll
      for (int mt = 0; mt < 4; ++mt)
#pragma unroll
        for (int nt = 0; nt < 4; ++nt)
          acc[mt][nt] = __builtin_amdgcn_mfma_f32_16x16x32_bf16(af[kk][mt], bf[kk][nt], acc[mt][nt], 0, 0, 0);
    __builtin_amdgcn_s_setprio(0);
    __syncthreads();
  }
#pragma unroll
  for (int mt = 0; mt < 4; ++mt) {
    int row = bm0 + wm0 + mt * 16 + ((ln >> 4) << 2);
#pragma unroll
    for (int nt = 0; nt < 4; ++nt) {
      int col = bn0 + wn0 + nt * 16 + (ln & 15);
      float bv = bias[col];
#pragma unroll
      for (int jj = 0; jj < 4; ++jj)
        C[(size_t)(row + jj) * 768 + col] = acc[mt][nt][jj] + bv;
    }
  }
}

// ---------------- flash attention: 32x32 MFMA, 4 waves x 32q, KVBLK=32 ----------------
// grid 16x48 = 768 blocks (XCD-chunked). S^T = mfma_32x32x16(K, Q): lane owns
// q = ln&31, 16 kv values (rows (reg&3)+8*(reg>>2)+4*l5). Softmax lane-local:
// 1 shfl_xor(32) for max (defer-max THR=8), sum deferred to epilogue.
// P^T -> PV B-frags: 8 cvt_pk + 4 permlane32_swap. O^T = mfma_32x32x16(V^T, P^T).
// K/V triple-buffered 24KB, counted vmcnt(2).
__global__ __launch_bounds__(256, 4) void k_attn(
    const __bf16* __restrict__ q, const __bf16* __restrict__ kv,
    const __bf16* __restrict__ vT, __bf16* __restrict__ ao) {
  __shared__ __align__(16) char ldsK[3][4096];
  __shared__ __align__(16) char ldsV[3][4096];
  const int tid = threadIdx.x, ln = tid & 63, w = tid >> 6;
  const int l5 = ln >> 5, l32 = ln & 31;
  int id = blockIdx.y * 16 + blockIdx.x;
  id = (id & 7) * 96 + (id >> 3);  // XCD chunking (768 % 8 == 0)
  const int qt = id & 15, bh = id >> 4;
  const int b = bh / HEADS, h = bh % HEADS;
  const int qrow = b * 2048 + qt * 128 + w * 32 + l32;

  const char* kgb = (const char*)(kv + ((size_t)b * 1024) * 1536 + h * 64);
  const char* vgb = (const char*)(vT + ((size_t)(b * 768 + h * 64)) * 1024);

  // staging geometry (rule #21: linear LDS dest, inverse-swizzled global src)
  const int krow = tid >> 3, kc = tid & 7;  // K tile: 32 rows x 128B
  const size_t ksrc = (size_t)krow * 3072 + (size_t)(((kc ^ (krow & 7)) << 4));
  const int vrow = tid >> 2, vc = tid & 3;  // V^T tile: 64 rows x 64B
  const size_t vsrc = (size_t)vrow * 2048 + (size_t)(((vc ^ ((vrow >> 1) & 3)) << 4));
  const int ldst = w << 10;  // wave-uniform LDS base within tile

  auto stageKV = [&](int t, int buf) {
    gload16(kgb + (size_t)t * 98304 + ksrc, ldsK[buf] + ldst);
    gload16(vgb + (size_t)t * 64 + vsrc, ldsV[buf] + ldst);
  };

  // Q fragments (pre-scaled by SCALE*log2e): qf[s] = Q[qrow][16s + 8*l5 + 0..7]
  bf16x8 qf[4];
#pragma unroll
  for (int s = 0; s < 4; ++s)
    qf[s] = *(const bf16x8*)(q + (size_t)qrow * 768 + h * 64 + 16 * s + 8 * l5);

  stageKV(0, 0);
  stageKV(1, 1);

  f32x16 accO[2] = {};
  float mrow = -1e30f, lrow = 0.f;

  asm volatile("s_waitcnt vmcnt(2)" ::: "memory");
  __builtin_amdgcn_s_barrier();

  for (int t = 0; t < 32; ++t) {
    if (t < 30) stageKV(t + 2, (t + 2) % 3);
    const char* bufK = ldsK[t % 3];
    const char* bufV = ldsV[t % 3];

    // S^T = K . Q^T
    f32x16 s16 = {};
    __builtin_amdgcn_s_setprio(1);
#pragma unroll
    for (int s = 0; s < 4; ++s) {
      bf16x8 kf = *(const bf16x8*)(bufK + l32 * 128 + (((2 * s + l5) ^ (l32 & 7)) << 4));
      s16 = __builtin_amdgcn_mfma_f32_32x32x16_bf16(kf, qf[s], s16, 0, 0, 0);
    }
    __builtin_amdgcn_s_setprio(0);

    // online softmax (exp2 domain), lane-local: q=l32, kv = (i&3)+8*(i>>2)+4*l5
    float lm = s16[0];
#pragma unroll
    for (int i = 1; i < 16; ++i) lm = fmaxf(lm, s16[i]);
    if (!__all(lm <= mrow + 8.0f)) {
      float mx = fmaxf(lm, __shfl_xor(lm, 32, 64));
      float mn = fmaxf(mrow, mx);
      float corr = exp2_fast(mrow - mn);
      mrow = mn;
      lrow *= corr;
#pragma unroll
      for (int dt = 0; dt < 2; ++dt)
#pragma unroll
        for (int i = 0; i < 16; ++i) accO[dt][i] *= corr;
    }
    float p[16];
    float ps = 0.f;
#pragma unroll
    for (int i = 0; i < 16; ++i) {
      p[i] = exp2_fast(s16[i] - mrow);
      ps += p[i];
    }
    lrow += ps;

    // P^T -> PV B-frags: c0[j]=(kv 8j+4l5+0,+1), c1[j]=(+2,+3); swap32 pairs
    uint32_t c0[4], c1[4];
#pragma unroll
    for (int j = 0; j < 4; ++j) {
      c0[j] = cvtpk(p[4 * j], p[4 * j + 1]);
      c1[j] = cvtpk(p[4 * j + 2], p[4 * j + 3]);
    }
    uint32_t w00 = c0[0], w02 = c0[1];
    asm("v_permlane32_swap_b32 %0, %1" : "+v"(w00), "+v"(w02));
    uint32_t w01 = c1[0], w03 = c1[1];
    asm("v_permlane32_swap_b32 %0, %1" : "+v"(w01), "+v"(w03));
    uint32_t w10 = c0[2], w12 = c0[3];
    asm("v_permlane32_swap_b32 %0, %1" : "+v"(w10), "+v"(w12));
    uint32_t w11 = c1[2], w13 = c1[3];
    asm("v_permlane32_swap_b32 %0, %1" : "+v"(w11), "+v"(w13));
    union { uint32_t u[4]; bf16x8 v; } pk0, pk1;
    pk0.u[0] = w00; pk0.u[1] = w01; pk0.u[2] = w02; pk0.u[3] = w03;  // ks=0: kv 0-15
    pk1.u[0] = w10; pk1.u[1] = w11; pk1.u[2] = w12; pk1.u[3] = w13;  // ks=1: kv 16-31

    // O^T += V^T . P^T
    __builtin_amdgcn_s_setprio(1);
#pragma unroll
    for (int dt = 0; dt < 2; ++dt) {
      int vr = dt * 32 + l32;
      bf16x8 vf0 = *(const bf16x8*)(bufV + vr * 64 + (((0 + l5) ^ ((vr >> 1) & 3)) << 4));
      accO[dt] = __builtin_amdgcn_mfma_f32_32x32x16_bf16(vf0, pk0.v, accO[dt], 0, 0, 0);
      bf16x8 vf1 = *(const bf16x8*)(bufV + vr * 64 + (((2 + l5) ^ ((vr >> 1) & 3)) << 4));
      accO[dt] = __builtin_amdgcn_mfma_f32_32x32x16_bf16(vf1, pk1.v, accO[dt], 0, 0, 0);
    }
    __builtin_amdgcn_s_setprio(0);

    if (t < 30) {
      asm volatile("s_waitcnt vmcnt(2)" ::: "memory");
      __builtin_amdgcn_s_barrier();
    } else if (t == 30) {
      asm volatile("s_waitcnt vmcnt(0)" ::: "memory");
      __builtin_amdgcn_s_barrier();
    }
  }

  // epilogue: lrow across l5 halves; O^T rows d = dt*32 + 8j + 4*l5 + (0..3)
  float l = lrow + __shfl_xor(lrow, 32, 64);
  float inv = 1.0f / l;
  size_t rowb = (size_t)qrow * 768 + h * 64;
#pragma unroll
  for (int dt = 0; dt < 2; ++dt)
#pragma unroll
    for (int j = 0; j < 4; ++j) {
      bf16x4 o;
#pragma unroll
      for (int i = 0; i < 4; ++i) o[i] = (__bf16)(accO[dt][4 * j + i] * inv);
      *(bf16x4*)(ao + rowb + dt * 32 + 8 * j + 4 * l5) = o;
    }
}

extern "C" void kernel_launch(void* const* d_in, const int* in_sizes, int n_in,
                              void* d_out, int out_size, void* d_ws, size_t ws_size,
                              hipStream_t stream) {
  const float* x = (const float*)d_in[0];
  const float* r = (const float*)d_in[1];
  const float* Wq = (const float*)d_in[2];
  const float* Wkv = (const float*)d_in[3];
  const float* Wp = (const float*)d_in[4];
  const float* bp = (const float*)d_in[5];

  char* ws = (char*)d_ws;
  __bf16* xb  = (__bf16*)ws; ws += (size_t)6291456 * 2;  // x bf16 (8192x768)
  __bf16* rb  = (__bf16*)ws; ws += (size_t)3145728 * 2;  // r bf16 (4096x768)
  __bf16* wqt = (__bf16*)ws; ws += (size_t)589824 * 2;   // W_q^T * SCALE*log2e
  __bf16* wkvt= (__bf16*)ws; ws += (size_t)1179648 * 2;  // W_kv^T (1536x768)
  __bf16* wpt = (__bf16*)ws; ws += (size_t)589824 * 2;   // W_proj^T (768x768)
  __bf16* qb  = (__bf16*)ws; ws += (size_t)6291456 * 2;  // q (8192x768), pre-scaled
  __bf16* kvb = (__bf16*)ws; ws += (size_t)6291456 * 2;  // kv (K half valid)
  __bf16* vT  = (__bf16*)ws; ws += (size_t)3145728 * 2;  // v^T (4 x 768 x 1024)
  __bf16* ao  = (__bf16*)ws;                              // attn out (8192x768)

  k_cast2<<<9216, 256, 0, stream>>>(x, r, xb, rb);
  k_twc3<<<dim3(48, 24, 3), 256, 0, stream>>>(Wq, Wkv, Wp, wqt, wkvt, wpt);
  k_gemm12<<<768, 256, 0, stream>>>(xb, rb, wqt, wkvt, qb, kvb, vT);
  k_attn<<<dim3(16, 48), 256, 0, stream>>>(qb, kvb, vT, ao);
  k_gemmP<<<dim3(6, 64), 256, 0, stream>>>(ao, wpt, (float*)d_out, bp);
}

// Round 7
// 101.038 us; speedup vs baseline: 1.1990x; 1.0131x over previous
//
#include <hip/hip_runtime.h>
#include <hip/hip_bf16.h>
#include <cstdint>

#define HEADS 12

typedef __attribute__((ext_vector_type(8))) __bf16 bf16x8;
typedef __attribute__((ext_vector_type(4))) __bf16 bf16x4;
typedef __attribute__((ext_vector_type(4))) float f32x4;
typedef __attribute__((ext_vector_type(16))) float f32x16;

#define AS1 __attribute__((address_space(1)))
#define AS3 __attribute__((address_space(3)))

__device__ __forceinline__ void gload16(const void* src, void* lds) {
  __builtin_amdgcn_global_load_lds((AS1 void*)src, (AS3 void*)lds, 16, 0, 0);
}

__device__ __forceinline__ uint32_t cvtpk(float lo, float hi) {
  uint32_t r;
  asm("v_cvt_pk_bf16_f32 %0, %1, %2" : "=v"(r) : "v"(lo), "v"(hi));
  return r;
}

__device__ __forceinline__ float exp2_fast(float x) {
  float r;
  asm("v_exp_f32 %0, %1" : "=v"(r) : "v"(x));
  return r;
}

// ---------------- cast fp32 -> bf16: x (6291456) then r (3145728) ----------------
__global__ void k_cast2(const float* __restrict__ x, const float* __restrict__ r,
                        __bf16* __restrict__ xb, __bf16* __restrict__ rb) {
  int i = (blockIdx.x * 256 + threadIdx.x) * 4;
  const float* src;
  __bf16* dst;
  int off;
  if (i < 6291456) { src = x; dst = xb; off = i; }
  else             { src = r; dst = rb; off = i - 6291456; }
  float4 v = *(const float4*)(src + off);
  bf16x4 o;
  o[0] = (__bf16)v.x; o[1] = (__bf16)v.y; o[2] = (__bf16)v.z; o[3] = (__bf16)v.w;
  *(bf16x4*)(dst + off) = o;
}

// ------------- transpose+cast all 3 weights: W[K][N] f32 -> Wt[N][K] bf16 (×scale) -------------
__global__ void k_twc3(const float* __restrict__ Wq, const float* __restrict__ Wkv,
                       const float* __restrict__ Wp, __bf16* __restrict__ wqt,
                       __bf16* __restrict__ wkvt, __bf16* __restrict__ wpt) {
  __shared__ float tile[32][33];
  const float* W; __bf16* Wt; int N; float scale;
  if (blockIdx.z == 0)      { W = Wq;  Wt = wqt;  N = 768;  scale = 0.18033688011112042f; }
  else if (blockIdx.z == 1) { W = Wkv; Wt = wkvt; N = 1536; scale = 1.0f; }
  else                      { W = Wp;  Wt = wpt;  N = 768;  scale = 1.0f; }
  int nt = blockIdx.x, kt = blockIdx.y;
  if (nt * 32 >= N) return;
  int c = threadIdx.x & 31, r0 = threadIdx.x >> 5;
#pragma unroll
  for (int i = 0; i < 4; ++i) {
    int r = r0 + i * 8;
    tile[r][c] = W[(size_t)(kt * 32 + r) * N + nt * 32 + c];
  }
  __syncthreads();
#pragma unroll
  for (int i = 0; i < 4; ++i) {
    int r = r0 + i * 8;
    Wt[(size_t)(nt * 32 + r) * 768 + kt * 32 + c] = (__bf16)(tile[c][r] * scale);
  }
}

// ---------------- fused Q-proj + KV-proj GEMM (768 blocks, flat id) ----------------
// id<384: qb[8192x768] = xb @ wqt^T (row-major).
// id>=384: K/V written in MFMA-fragment-blocked layouts:
//   K block (b,h,t): [s(4)][l5(2)][kv(32)][8d]  (4KB, = attn LDS image)
//   V block (b,h,t): [dt(2)][ks(2)][l5(2)][dl(32)][8kv] (4KB, = attn reg-frag image)
__global__ __launch_bounds__(256, 2) void k_gemm12(
    const __bf16* __restrict__ xb, const __bf16* __restrict__ rb,
    const __bf16* __restrict__ wqt, const __bf16* __restrict__ wkvt,
    __bf16* __restrict__ qb, __bf16* __restrict__ kbp, __bf16* __restrict__ vbp) {
  __shared__ __align__(16) char ldsA[2][16384];
  __shared__ __align__(16) char ldsB[2][16384];
  const int tid = threadIdx.x;
  const int ln = tid & 63;
  const int w = tid >> 6;
  int id = blockIdx.x;
  id = (id & 7) * 96 + (id >> 3);  // XCD chunking (768 % 8 == 0)
  const __bf16* A; const __bf16* Bt; int bm0, bn0; bool qpart;
  if (id < 384) { A = xb; Bt = wqt;  bm0 = (id / 6) * 128;  bn0 = (id % 6) * 128;  qpart = true; }
  else { int i2 = id - 384; A = rb; Bt = wkvt; bm0 = (i2 / 12) * 128; bn0 = (i2 % 12) * 128; qpart = false; }
  const int wm0 = (w >> 1) * 64, wn0 = (w & 1) * 64;

  auto stage = [&](char* lds, const __bf16* G, int row0, int k0) {
    const char* gb = (const char*)(G + (size_t)row0 * 768 + k0);
#pragma unroll
    for (int c = 0; c < 4; ++c) {
      int off = c * 4096 + tid * 16;
      int row = off >> 7;
      int s = ((off >> 4) & 7) ^ (row & 7);
      gload16(gb + (size_t)row * 1536 + (s << 4), lds + c * 4096 + (w << 10));
    }
  };

  f32x4 acc[4][4] = {};
  stage(ldsA[0], A, bm0, 0);
  stage(ldsB[0], Bt, bn0, 0);
  __syncthreads();
  for (int kt = 0; kt < 12; ++kt) {
    const char* bufA = ldsA[kt & 1];
    const char* bufB = ldsB[kt & 1];
    if (kt + 1 < 12) {
      stage(ldsA[(kt + 1) & 1], A, bm0, (kt + 1) << 6);
      stage(ldsB[(kt + 1) & 1], Bt, bn0, (kt + 1) << 6);
    }
    bf16x8 af[2][4], bf[2][4];
#pragma unroll
    for (int kk = 0; kk < 2; ++kk)
#pragma unroll
      for (int mt = 0; mt < 4; ++mt) {
        int row = wm0 + mt * 16 + (ln & 15);
        af[kk][mt] = *(const bf16x8*)(bufA + row * 128 + (((kk * 4 + (ln >> 4)) ^ (row & 7)) << 4));
      }
#pragma unroll
    for (int kk = 0; kk < 2; ++kk)
#pragma unroll
      for (int nt = 0; nt < 4; ++nt) {
        int row = wn0 + nt * 16 + (ln & 15);
        bf[kk][nt] = *(const bf16x8*)(bufB + row * 128 + (((kk * 4 + (ln >> 4)) ^ (row & 7)) << 4));
      }
    __builtin_amdgcn_s_setprio(1);
#pragma unroll
    for (int kk = 0; kk < 2; ++kk)
#pragma unroll
      for (int mt = 0; mt < 4; ++mt)
#pragma unroll
        for (int nt = 0; nt < 4; ++nt)
          acc[mt][nt] = __builtin_amdgcn_mfma_f32_16x16x32_bf16(af[kk][mt], bf[kk][nt], acc[mt][nt], 0, 0, 0);
    __builtin_amdgcn_s_setprio(0);
    __syncthreads();
  }
#pragma unroll
  for (int mt = 0; mt < 4; ++mt) {
    int row = bm0 + wm0 + mt * 16 + ((ln >> 4) << 2);
#pragma unroll
    for (int nt = 0; nt < 4; ++nt) {
      int col = bn0 + wn0 + nt * 16 + (ln & 15);
      if (qpart) {
#pragma unroll
        for (int jj = 0; jj < 4; ++jj)
          qb[(size_t)(row + jj) * 768 + col] = (__bf16)acc[mt][nt][jj];
      } else {
        int bb = row >> 10, kvg = row & 1023;
        int t32 = kvg >> 5, kvl = kvg & 31;  // kvl quad-aligned
        if (col < 768) {
          int hh = col >> 6, d = col & 63;
          size_t base = ((size_t)(bb * 12 + hh) * 32 + t32) * 2048
                      + (size_t)(((((d >> 4) << 1) + ((d >> 3) & 1)) * 32 + kvl) * 8 + (d & 7));
#pragma unroll
          for (int jj = 0; jj < 4; ++jj)
            kbp[base + jj * 8] = (__bf16)acc[mt][nt][jj];
        } else {
          int cv = col - 768;
          int hh = cv >> 6, d = cv & 63;
          size_t base = ((size_t)(bb * 12 + hh) * 32 + t32) * 2048
                      + (size_t)((((((d >> 5) << 1) + (kvl >> 4)) * 2 + ((kvl >> 3) & 1)) * 32 + (d & 31)) * 8 + (kvl & 7));
          bf16x4 o;
#pragma unroll
          for (int jj = 0; jj < 4; ++jj) o[jj] = (__bf16)acc[mt][nt][jj];
          *(bf16x4*)(vbp + base) = o;
        }
      }
    }
  }
}

// ---------------- out-proj GEMM: C[M][N] f32 = A @ Bt^T + bias ----------------
__global__ __launch_bounds__(256, 2) void k_gemmP(
    const __bf16* __restrict__ A, const __bf16* __restrict__ Bt,
    float* __restrict__ C, const float* __restrict__ bias) {
  __shared__ __align__(16) char ldsA[2][16384];
  __shared__ __align__(16) char ldsB[2][16384];
  const int tid = threadIdx.x;
  const int ln = tid & 63;
  const int w = tid >> 6;
  int bid = blockIdx.y * 6 + blockIdx.x;
  bid = (bid & 7) * 48 + (bid >> 3);  // 384 % 8 == 0
  const int bm0 = (bid / 6) * 128, bn0 = (bid % 6) * 128;
  const int wm0 = (w >> 1) * 64, wn0 = (w & 1) * 64;

  auto stage = [&](char* lds, const __bf16* G, int row0, int k0) {
    const char* gb = (const char*)(G + (size_t)row0 * 768 + k0);
#pragma unroll
    for (int c = 0; c < 4; ++c) {
      int off = c * 4096 + tid * 16;
      int row = off >> 7;
      int s = ((off >> 4) & 7) ^ (row & 7);
      gload16(gb + (size_t)row * 1536 + (s << 4), lds + c * 4096 + (w << 10));
    }
  };

  f32x4 acc[4][4] = {};
  stage(ldsA[0], A, bm0, 0);
  stage(ldsB[0], Bt, bn0, 0);
  __syncthreads();
  for (int kt = 0; kt < 12; ++kt) {
    const char* bufA = ldsA[kt & 1];
    const char* bufB = ldsB[kt & 1];
    if (kt + 1 < 12) {
      stage(ldsA[(kt + 1) & 1], A, bm0, (kt + 1) << 6);
      stage(ldsB[(kt + 1) & 1], Bt, bn0, (kt + 1) << 6);
    }
    bf16x8 af[2][4], bf[2][4];
#pragma unroll
    for (int kk = 0; kk < 2; ++kk)
#pragma unroll
      for (int mt = 0; mt < 4; ++mt) {
        int row = wm0 + mt * 16 + (ln & 15);
        af[kk][mt] = *(const bf16x8*)(bufA + row * 128 + (((kk * 4 + (ln >> 4)) ^ (row & 7)) << 4));
      }
#pragma unroll
    for (int kk = 0; kk < 2; ++kk)
#pragma unroll
      for (int nt = 0; nt < 4; ++nt) {
        int row = wn0 + nt * 16 + (ln & 15);
        bf[kk][nt] = *(const bf16x8*)(bufB + row * 128 + (((kk * 4 + (ln >> 4)) ^ (row & 7)) << 4));
      }
    __builtin_amdgcn_s_setprio(1);
#pragma unroll
    for (int kk = 0; kk < 2; ++kk)
#pragma unroll
      for (int mt = 0; mt < 4; ++mt)
#pragma unroll
        for (int nt = 0; nt < 4; ++nt)
          acc[mt][nt] = __builtin_amdgcn_mfma_f32_16x16x32_bf16(af[kk][mt], bf[kk][nt], acc[mt][nt], 0, 0, 0);
    __builtin_amdgcn_s_setprio(0);
    __syncthreads();
  }
#pragma unroll
  for (int mt = 0; mt < 4; ++mt) {
    int row = bm0 + wm0 + mt * 16 + ((ln >> 4) << 2);
#pragma unroll
    for (int nt = 0; nt < 4; ++nt) {
      int col = bn0 + wn0 + nt * 16 + (ln & 15);
      float bv = bias[col];
#pragma unroll
      for (int jj = 0; jj < 4; ++jj)
        C[(size_t)(row + jj) * 768 + col] = acc[mt][nt][jj] + bv;
    }
  }
}

// ---------------- flash attention: 32x32 MFMA, blocked K/V, KVBLK=64 ----------------
// 4 waves x 32q, grid 768 (XCD-chunked). K via LDS (flat 8KB memcpy stage,
// linear conflict-free reads, 3-deep). V direct global->reg (L2-resident,
// coalesced 512B segments, issued at tile top, hidden under QK+softmax).
// Softmax exp2-domain, defer-max, lane-partial lrow. No manual vmcnt in loop:
// compiler's V-wait before PV necessarily retires K(t+1) staging (FIFO order).
__global__ __launch_bounds__(256, 3) void k_attn(
    const __bf16* __restrict__ q, const __bf16* __restrict__ kb,
    const __bf16* __restrict__ vb, __bf16* __restrict__ ao) {
  __shared__ __align__(16) char ldsK[3][8192];
  const int tid = threadIdx.x, ln = tid & 63;
  const int l5 = ln >> 5, l32 = ln & 31, w = tid >> 6;
  int id = blockIdx.y * 16 + blockIdx.x;
  id = (id & 7) * 96 + (id >> 3);  // XCD chunking (768 % 8 == 0)
  const int qt = id & 15, bh = id >> 4;
  const int b = bh / HEADS, h = bh % HEADS;
  const int qrow = b * 2048 + qt * 128 + w * 32 + l32;

  const char* kbase = (const char*)kb + (size_t)bh * 131072;
  const __bf16* vbase = vb + (size_t)bh * 65536;
  const int vchunk = l5 * 256 + l32 * 8;  // lane offset within a (dt,ks) group

  auto stageK = [&](int t, int buf) {
    gload16(kbase + (size_t)t * 8192 + tid * 16, ldsK[buf] + tid * 16);
    gload16(kbase + (size_t)t * 8192 + 4096 + tid * 16, ldsK[buf] + 4096 + tid * 16);
  };

  // Q fragments (pre-scaled by SCALE*log2e): qf[s] = Q[qrow][h*64 + 16s + 8l5 ..]
  bf16x8 qf[4];
#pragma unroll
  for (int s = 0; s < 4; ++s)
    qf[s] = *(const bf16x8*)(q + (size_t)qrow * 768 + h * 64 + 16 * s + 8 * l5);

  stageK(0, 0);
  stageK(1, 1);

  f32x16 accO[2] = {};
  float mrow = -1e30f, lrow = 0.f;

  asm volatile("s_waitcnt vmcnt(0)" ::: "memory");
  __builtin_amdgcn_s_barrier();

  for (int t = 0; t < 16; ++t) {
    const char* bufK = ldsK[t % 3];

    // V fragments direct from global (blocked layout, coalesced)
    bf16x8 vf[2][2][2];
    {
      const __bf16* vt = vbase + (size_t)(2 * t) * 2048 + vchunk;
#pragma unroll
      for (int nt = 0; nt < 2; ++nt)
#pragma unroll
        for (int dt = 0; dt < 2; ++dt)
#pragma unroll
          for (int ks = 0; ks < 2; ++ks)
            vf[nt][dt][ks] = *(const bf16x8*)(vt + nt * 2048 + (dt * 2 + ks) * 512);
    }
    if (t < 14) stageK(t + 2, (t + 2) % 3);

    // S^T = K . Q^T  (two independent chains nt=0,1)
    f32x16 s16[2] = {};
    __builtin_amdgcn_s_setprio(1);
#pragma unroll
    for (int s = 0; s < 4; ++s) {
      bf16x8 kf0 = *(const bf16x8*)(bufK + (s * 2 + l5) * 512 + l32 * 16);
      s16[0] = __builtin_amdgcn_mfma_f32_32x32x16_bf16(kf0, qf[s], s16[0], 0, 0, 0);
      bf16x8 kf1 = *(const bf16x8*)(bufK + 4096 + (s * 2 + l5) * 512 + l32 * 16);
      s16[1] = __builtin_amdgcn_mfma_f32_32x32x16_bf16(kf1, qf[s], s16[1], 0, 0, 0);
    }
    __builtin_amdgcn_s_setprio(0);

    // online softmax (exp2 domain), lane owns q=l32; kv = nt*32 + (i&3)+8*(i>>2)+4*l5
    float lm = s16[0][0];
#pragma unroll
    for (int nt = 0; nt < 2; ++nt)
#pragma unroll
      for (int i = 0; i < 16; ++i) lm = fmaxf(lm, s16[nt][i]);
    if (!__all(lm <= mrow + 8.0f)) {
      float mx = fmaxf(lm, __shfl_xor(lm, 32, 64));
      float mn = fmaxf(mrow, mx);
      float corr = exp2_fast(mrow - mn);
      mrow = mn;
      lrow *= corr;
#pragma unroll
      for (int dt = 0; dt < 2; ++dt)
#pragma unroll
        for (int i = 0; i < 16; ++i) accO[dt][i] *= corr;
    }
    float ps = 0.f;
#pragma unroll
    for (int nt = 0; nt < 2; ++nt)
#pragma unroll
      for (int i = 0; i < 16; ++i) {
        float e = exp2_fast(s16[nt][i] - mrow);
        s16[nt][i] = e;  // reuse as p
        ps += e;
      }
    lrow += ps;

    // P^T -> PV B-frags per nt: 8 cvt_pk + 4 permlane32_swap
    bf16x8 pk[2][2];
#pragma unroll
    for (int nt = 0; nt < 2; ++nt) {
      uint32_t c0[4], c1[4];
#pragma unroll
      for (int j = 0; j < 4; ++j) {
        c0[j] = cvtpk(s16[nt][4 * j], s16[nt][4 * j + 1]);
        c1[j] = cvtpk(s16[nt][4 * j + 2], s16[nt][4 * j + 3]);
      }
      uint32_t w00 = c0[0], w02 = c0[1];
      asm("v_permlane32_swap_b32 %0, %1" : "+v"(w00), "+v"(w02));
      uint32_t w01 = c1[0], w03 = c1[1];
      asm("v_permlane32_swap_b32 %0, %1" : "+v"(w01), "+v"(w03));
      uint32_t w10 = c0[2], w12 = c0[3];
      asm("v_permlane32_swap_b32 %0, %1" : "+v"(w10), "+v"(w12));
      uint32_t w11 = c1[2], w13 = c1[3];
      asm("v_permlane32_swap_b32 %0, %1" : "+v"(w11), "+v"(w13));
      union { uint32_t u[4]; bf16x8 v; } pk0, pk1;
      pk0.u[0] = w00; pk0.u[1] = w01; pk0.u[2] = w02; pk0.u[3] = w03;  // kv 0-15 of nt
      pk1.u[0] = w10; pk1.u[1] = w11; pk1.u[2] = w12; pk1.u[3] = w13;  // kv 16-31 of nt
      pk[nt][0] = pk0.v;
      pk[nt][1] = pk1.v;
    }

    // O^T += V^T . P^T  (compiler inserts minimal vmcnt for vf here)
    __builtin_amdgcn_s_setprio(1);
#pragma unroll
    for (int nt = 0; nt < 2; ++nt)
#pragma unroll
      for (int ks = 0; ks < 2; ++ks) {
        accO[0] = __builtin_amdgcn_mfma_f32_32x32x16_bf16(vf[nt][0][ks], pk[nt][ks], accO[0], 0, 0, 0);
        accO[1] = __builtin_amdgcn_mfma_f32_32x32x16_bf16(vf[nt][1][ks], pk[nt][ks], accO[1], 0, 0, 0);
      }
    __builtin_amdgcn_s_setprio(0);

    __builtin_amdgcn_sched_barrier(0);
    __builtin_amdgcn_s_barrier();
  }

  // epilogue: lrow across l5 halves; O^T rows d = dt*32 + 8j + 4*l5 + (0..3)
  float l = lrow + __shfl_xor(lrow, 32, 64);
  float inv = 1.0f / l;
  size_t rowb = (size_t)qrow * 768 + h * 64;
#pragma unroll
  for (int dt = 0; dt < 2; ++dt)
#pragma unroll
    for (int j = 0; j < 4; ++j) {
      bf16x4 o;
#pragma unroll
      for (int i = 0; i < 4; ++i) o[i] = (__bf16)(accO[dt][4 * j + i] * inv);
      *(bf16x4*)(ao + rowb + dt * 32 + 8 * j + 4 * l5) = o;
    }
}

extern "C" void kernel_launch(void* const* d_in, const int* in_sizes, int n_in,
                              void* d_out, int out_size, void* d_ws, size_t ws_size,
                              hipStream_t stream) {
  const float* x = (const float*)d_in[0];
  const float* r = (const float*)d_in[1];
  const float* Wq = (const float*)d_in[2];
  const float* Wkv = (const float*)d_in[3];
  const float* Wp = (const float*)d_in[4];
  const float* bp = (const float*)d_in[5];

  char* ws = (char*)d_ws;
  __bf16* xb  = (__bf16*)ws; ws += (size_t)6291456 * 2;  // x bf16 (8192x768)
  __bf16* rb  = (__bf16*)ws; ws += (size_t)3145728 * 2;  // r bf16 (4096x768)
  __bf16* wqt = (__bf16*)ws; ws += (size_t)589824 * 2;   // W_q^T * SCALE*log2e
  __bf16* wkvt= (__bf16*)ws; ws += (size_t)1179648 * 2;  // W_kv^T (1536x768)
  __bf16* wpt = (__bf16*)ws; ws += (size_t)589824 * 2;   // W_proj^T (768x768)
  __bf16* qb  = (__bf16*)ws; ws += (size_t)6291456 * 2;  // q (8192x768), pre-scaled
  __bf16* kbk = (__bf16*)ws; ws += (size_t)3145728 * 2;  // K blocked (48 bh x 32 t x 4KB)
  __bf16* vbk = (__bf16*)ws; ws += (size_t)3145728 * 2;  // V blocked (48 bh x 32 t x 4KB)
  __bf16* ao  = (__bf16*)ws;                              // attn out (8192x768)

  k_cast2<<<9216, 256, 0, stream>>>(x, r, xb, rb);
  k_twc3<<<dim3(48, 24, 3), 256, 0, stream>>>(Wq, Wkv, Wp, wqt, wkvt, wpt);
  k_gemm12<<<768, 256, 0, stream>>>(xb, rb, wqt, wkvt, qb, kbk, vbk);
  k_attn<<<dim3(16, 48), 256, 0, stream>>>(qb, kbk, vbk, ao);
  k_gemmP<<<dim3(6, 64), 256, 0, stream>>>(ao, wpt, (float*)d_out, bp);
}

// Round 8
// 99.960 us; speedup vs baseline: 1.2119x; 1.0108x over previous
//
#include <hip/hip_runtime.h>
#include <hip/hip_bf16.h>
#include <cstdint>

#define HEADS 12

typedef __attribute__((ext_vector_type(8))) __bf16 bf16x8;
typedef __attribute__((ext_vector_type(4))) __bf16 bf16x4;
typedef __attribute__((ext_vector_type(4))) float f32x4;
typedef __attribute__((ext_vector_type(16))) float f32x16;

#define AS1 __attribute__((address_space(1)))
#define AS3 __attribute__((address_space(3)))

__device__ __forceinline__ void gload16(const void* src, void* lds) {
  __builtin_amdgcn_global_load_lds((AS1 void*)src, (AS3 void*)lds, 16, 0, 0);
}

__device__ __forceinline__ uint32_t cvtpk(float lo, float hi) {
  uint32_t r;
  asm("v_cvt_pk_bf16_f32 %0, %1, %2" : "=v"(r) : "v"(lo), "v"(hi));
  return r;
}

__device__ __forceinline__ float exp2_fast(float x) {
  float r;
  asm("v_exp_f32 %0, %1" : "=v"(r) : "v"(x));
  return r;
}

// ---------------- cast fp32 -> bf16: x (6291456) then r (3145728) ----------------
__global__ void k_cast2(const float* __restrict__ x, const float* __restrict__ r,
                        __bf16* __restrict__ xb, __bf16* __restrict__ rb) {
  int i = (blockIdx.x * 256 + threadIdx.x) * 4;
  const float* src;
  __bf16* dst;
  int off;
  if (i < 6291456) { src = x; dst = xb; off = i; }
  else             { src = r; dst = rb; off = i - 6291456; }
  float4 v = *(const float4*)(src + off);
  bf16x4 o;
  o[0] = (__bf16)v.x; o[1] = (__bf16)v.y; o[2] = (__bf16)v.z; o[3] = (__bf16)v.w;
  *(bf16x4*)(dst + off) = o;
}

// ------------- transpose+cast all 3 weights: W[K][N] f32 -> Wt[N][K] bf16 (×scale) -------------
__global__ void k_twc3(const float* __restrict__ Wq, const float* __restrict__ Wkv,
                       const float* __restrict__ Wp, __bf16* __restrict__ wqt,
                       __bf16* __restrict__ wkvt, __bf16* __restrict__ wpt) {
  __shared__ float tile[32][33];
  const float* W; __bf16* Wt; int N; float scale;
  if (blockIdx.z == 0)      { W = Wq;  Wt = wqt;  N = 768;  scale = 0.18033688011112042f; }
  else if (blockIdx.z == 1) { W = Wkv; Wt = wkvt; N = 1536; scale = 1.0f; }
  else                      { W = Wp;  Wt = wpt;  N = 768;  scale = 1.0f; }
  int nt = blockIdx.x, kt = blockIdx.y;
  if (nt * 32 >= N) return;
  int c = threadIdx.x & 31, r0 = threadIdx.x >> 5;
#pragma unroll
  for (int i = 0; i < 4; ++i) {
    int r = r0 + i * 8;
    tile[r][c] = W[(size_t)(kt * 32 + r) * N + nt * 32 + c];
  }
  __syncthreads();
#pragma unroll
  for (int i = 0; i < 4; ++i) {
    int r = r0 + i * 8;
    Wt[(size_t)(nt * 32 + r) * 768 + kt * 32 + c] = (__bf16)(tile[c][r] * scale);
  }
}

// ---------------- fused Q-proj + KV-proj GEMM (768 blocks, flat id) ----------------
// id<384: qb[8192x768] = xb @ wqt^T (row-major).
// id>=384: K/V in MFMA-fragment-blocked layouts (identical to R7, attn-validated):
//   K block (bh,t32): elem = dc*256 + kvl*8 + (d&7), dc = ((d>>4)<<1)+((d>>3)&1)
//   V block (bh,t32): elem = (((d5*2+kv4)*2+kv3)*32 + (d&31))*8 + (kvl&7)
// Epilogue via LDS (reuse ldsA, 32KB): dump acc as bf16 (V transposed), barrier,
// read 16B contiguous fragments, store bf16x8 -> K/V writes are sequential 4KB runs.
__global__ __launch_bounds__(256, 2) void k_gemm12(
    const __bf16* __restrict__ xb, const __bf16* __restrict__ rb,
    const __bf16* __restrict__ wqt, const __bf16* __restrict__ wkvt,
    __bf16* __restrict__ qb, __bf16* __restrict__ kbp, __bf16* __restrict__ vbp) {
  __shared__ __align__(16) char ldsA[2][16384];
  __shared__ __align__(16) char ldsB[2][16384];
  const int tid = threadIdx.x;
  const int ln = tid & 63;
  const int w = tid >> 6;
  int id = blockIdx.x;
  id = (id & 7) * 96 + (id >> 3);  // XCD chunking (768 % 8 == 0)
  const __bf16* A; const __bf16* Bt; int bm0, bn0; bool qpart;
  if (id < 384) { A = xb; Bt = wqt;  bm0 = (id / 6) * 128;  bn0 = (id % 6) * 128;  qpart = true; }
  else { int i2 = id - 384; A = rb; Bt = wkvt; bm0 = (i2 / 12) * 128; bn0 = (i2 % 12) * 128; qpart = false; }
  const int wm0 = (w >> 1) * 64, wn0 = (w & 1) * 64;

  auto stage = [&](char* lds, const __bf16* G, int row0, int k0) {
    const char* gb = (const char*)(G + (size_t)row0 * 768 + k0);
#pragma unroll
    for (int c = 0; c < 4; ++c) {
      int off = c * 4096 + tid * 16;
      int row = off >> 7;
      int s = ((off >> 4) & 7) ^ (row & 7);
      gload16(gb + (size_t)row * 1536 + (s << 4), lds + c * 4096 + (w << 10));
    }
  };

  f32x4 acc[4][4] = {};
  stage(ldsA[0], A, bm0, 0);
  stage(ldsB[0], Bt, bn0, 0);
  __syncthreads();
  for (int kt = 0; kt < 12; ++kt) {
    const char* bufA = ldsA[kt & 1];
    const char* bufB = ldsB[kt & 1];
    if (kt + 1 < 12) {
      stage(ldsA[(kt + 1) & 1], A, bm0, (kt + 1) << 6);
      stage(ldsB[(kt + 1) & 1], Bt, bn0, (kt + 1) << 6);
    }
    bf16x8 af[2][4], bf[2][4];
#pragma unroll
    for (int kk = 0; kk < 2; ++kk)
#pragma unroll
      for (int mt = 0; mt < 4; ++mt) {
        int row = wm0 + mt * 16 + (ln & 15);
        af[kk][mt] = *(const bf16x8*)(bufA + row * 128 + (((kk * 4 + (ln >> 4)) ^ (row & 7)) << 4));
      }
#pragma unroll
    for (int kk = 0; kk < 2; ++kk)
#pragma unroll
      for (int nt = 0; nt < 4; ++nt) {
        int row = wn0 + nt * 16 + (ln & 15);
        bf[kk][nt] = *(const bf16x8*)(bufB + row * 128 + (((kk * 4 + (ln >> 4)) ^ (row & 7)) << 4));
      }
    __builtin_amdgcn_s_setprio(1);
#pragma unroll
    for (int kk = 0; kk < 2; ++kk)
#pragma unroll
      for (int mt = 0; mt < 4; ++mt)
#pragma unroll
        for (int nt = 0; nt < 4; ++nt)
          acc[mt][nt] = __builtin_amdgcn_mfma_f32_16x16x32_bf16(af[kk][mt], bf[kk][nt], acc[mt][nt], 0, 0, 0);
    __builtin_amdgcn_s_setprio(0);
    __syncthreads();
  }

  // ---- LDS-staged epilogue (32KB tile in ldsA) ----
  char* ldsT = &ldsA[0][0];
  const bool vpart = (!qpart) && (bn0 >= 768);
  if (!vpart) {
    // normal orientation: [row 128][col 128] bf16, 16B-slot swizzle by row&7
#pragma unroll
    for (int mt = 0; mt < 4; ++mt)
#pragma unroll
      for (int nt = 0; nt < 4; ++nt)
#pragma unroll
        for (int jj = 0; jj < 4; ++jj) {
          int rowl = wm0 + mt * 16 + ((ln >> 4) << 2) + jj;
          int colb = (wn0 + nt * 16 + (ln & 15)) * 2;
          *(__bf16*)(ldsT + rowl * 256 + (colb ^ ((rowl & 7) << 4))) = (__bf16)acc[mt][nt][jj];
        }
  } else {
    // transposed: [d 128][kv 128] bf16, swizzle by d&7
#pragma unroll
    for (int mt = 0; mt < 4; ++mt)
#pragma unroll
      for (int nt = 0; nt < 4; ++nt)
#pragma unroll
        for (int jj = 0; jj < 4; ++jj) {
          int dloc = wn0 + nt * 16 + (ln & 15);
          int kvb = (wm0 + mt * 16 + ((ln >> 4) << 2) + jj) * 2;
          *(__bf16*)(ldsT + dloc * 256 + (kvb ^ ((dloc & 7) << 4))) = (__bf16)acc[mt][nt][jj];
        }
  }
  __syncthreads();

  if (qpart) {
#pragma unroll
    for (int it = 0; it < 8; ++it) {
      int rowl = it * 16 + (tid >> 4);
      int colb = (tid & 15) * 16;
      bf16x8 v = *(const bf16x8*)(ldsT + rowl * 256 + (colb ^ ((rowl & 7) << 4)));
      *(bf16x8*)(qb + (size_t)(bm0 + rowl) * 768 + bn0 + (tid & 15) * 8) = v;
    }
  } else if (!vpart) {
    const int bb = bm0 >> 10, kvb0 = (bm0 & 1023) >> 5, hh0 = bn0 >> 6;
#pragma unroll
    for (int it = 0; it < 8; ++it) {
      int hh = it >> 2, t32 = it & 3;
      int dc = tid >> 5, kvl = tid & 31;
      int rowl = t32 * 32 + kvl;
      int colb = hh * 128 + (dc >> 1) * 32 + (dc & 1) * 16;
      bf16x8 v = *(const bf16x8*)(ldsT + rowl * 256 + (colb ^ ((rowl & 7) << 4)));
      *(bf16x8*)(kbp + ((size_t)(bb * 12 + hh0 + hh) * 32 + kvb0 + t32) * 2048 + tid * 8) = v;
    }
  } else {
    const int bb = bm0 >> 10, kvb0 = (bm0 & 1023) >> 5, hh0 = (bn0 - 768) >> 6;
#pragma unroll
    for (int it = 0; it < 8; ++it) {
      int hh = it >> 2, t32 = it & 3;
      int d = ((tid >> 7) << 5) + (tid & 31);
      int kvl8 = (((tid >> 6) & 1) << 4) + (((tid >> 5) & 1) << 3);
      int dloc = hh * 64 + d;
      int kvb = (t32 * 32 + kvl8) * 2;
      bf16x8 v = *(const bf16x8*)(ldsT + dloc * 256 + (kvb ^ ((dloc & 7) << 4)));
      *(bf16x8*)(vbp + ((size_t)(bb * 12 + hh0 + hh) * 32 + kvb0 + t32) * 2048 + tid * 8) = v;
    }
  }
}

// ---------------- out-proj GEMM: C[M][N] f32 = A @ Bt^T + bias ----------------
__global__ __launch_bounds__(256, 2) void k_gemmP(
    const __bf16* __restrict__ A, const __bf16* __restrict__ Bt,
    float* __restrict__ C, const float* __restrict__ bias) {
  __shared__ __align__(16) char ldsA[2][16384];
  __shared__ __align__(16) char ldsB[2][16384];
  const int tid = threadIdx.x;
  const int ln = tid & 63;
  const int w = tid >> 6;
  int bid = blockIdx.y * 6 + blockIdx.x;
  bid = (bid & 7) * 48 + (bid >> 3);  // 384 % 8 == 0
  const int bm0 = (bid / 6) * 128, bn0 = (bid % 6) * 128;
  const int wm0 = (w >> 1) * 64, wn0 = (w & 1) * 64;

  auto stage = [&](char* lds, const __bf16* G, int row0, int k0) {
    const char* gb = (const char*)(G + (size_t)row0 * 768 + k0);
#pragma unroll
    for (int c = 0; c < 4; ++c) {
      int off = c * 4096 + tid * 16;
      int row = off >> 7;
      int s = ((off >> 4) & 7) ^ (row & 7);
      gload16(gb + (size_t)row * 1536 + (s << 4), lds + c * 4096 + (w << 10));
    }
  };

  f32x4 acc[4][4] = {};
  stage(ldsA[0], A, bm0, 0);
  stage(ldsB[0], Bt, bn0, 0);
  __syncthreads();
  for (int kt = 0; kt < 12; ++kt) {
    const char* bufA = ldsA[kt & 1];
    const char* bufB = ldsB[kt & 1];
    if (kt + 1 < 12) {
      stage(ldsA[(kt + 1) & 1], A, bm0, (kt + 1) << 6);
      stage(ldsB[(kt + 1) & 1], Bt, bn0, (kt + 1) << 6);
    }
    bf16x8 af[2][4], bf[2][4];
#pragma unroll
    for (int kk = 0; kk < 2; ++kk)
#pragma unroll
      for (int mt = 0; mt < 4; ++mt) {
        int row = wm0 + mt * 16 + (ln & 15);
        af[kk][mt] = *(const bf16x8*)(bufA + row * 128 + (((kk * 4 + (ln >> 4)) ^ (row & 7)) << 4));
      }
#pragma unroll
    for (int kk = 0; kk < 2; ++kk)
#pragma unroll
      for (int nt = 0; nt < 4; ++nt) {
        int row = wn0 + nt * 16 + (ln & 15);
        bf[kk][nt] = *(const bf16x8*)(bufB + row * 128 + (((kk * 4 + (ln >> 4)) ^ (row & 7)) << 4));
      }
    __builtin_amdgcn_s_setprio(1);
#pragma unroll
    for (int kk = 0; kk < 2; ++kk)
#pragma unroll
      for (int mt = 0; mt < 4; ++mt)
#pragma unroll
        for (int nt = 0; nt < 4; ++nt)
          acc[mt][nt] = __builtin_amdgcn_mfma_f32_16x16x32_bf16(af[kk][mt], bf[kk][nt], acc[mt][nt], 0, 0, 0);
    __builtin_amdgcn_s_setprio(0);
    __syncthreads();
  }
#pragma unroll
  for (int mt = 0; mt < 4; ++mt) {
    int row = bm0 + wm0 + mt * 16 + ((ln >> 4) << 2);
#pragma unroll
    for (int nt = 0; nt < 4; ++nt) {
      int col = bn0 + wn0 + nt * 16 + (ln & 15);
      float bv = bias[col];
#pragma unroll
      for (int jj = 0; jj < 4; ++jj)
        C[(size_t)(row + jj) * 768 + col] = acc[mt][nt][jj] + bv;
    }
  }
}

// ---------------- flash attention: 32x32 MFMA, blocked K/V, KVBLK=64 ----------------
// 4 waves x 32q, grid 768 (XCD-chunked). K via LDS (flat 8KB memcpy stage,
// linear conflict-free reads, 3-deep). V direct global->reg (L2-resident,
// coalesced 512B segments, issued at tile top, hidden under QK+softmax).
__global__ __launch_bounds__(256, 3) void k_attn(
    const __bf16* __restrict__ q, const __bf16* __restrict__ kb,
    const __bf16* __restrict__ vb, __bf16* __restrict__ ao) {
  __shared__ __align__(16) char ldsK[3][8192];
  const int tid = threadIdx.x, ln = tid & 63;
  const int l5 = ln >> 5, l32 = ln & 31, w = tid >> 6;
  int id = blockIdx.y * 16 + blockIdx.x;
  id = (id & 7) * 96 + (id >> 3);  // XCD chunking (768 % 8 == 0)
  const int qt = id & 15, bh = id >> 4;
  const int b = bh / HEADS, h = bh % HEADS;
  const int qrow = b * 2048 + qt * 128 + w * 32 + l32;

  const char* kbase = (const char*)kb + (size_t)bh * 131072;
  const __bf16* vbase = vb + (size_t)bh * 65536;
  const int vchunk = l5 * 256 + l32 * 8;

  auto stageK = [&](int t, int buf) {
    gload16(kbase + (size_t)t * 8192 + tid * 16, ldsK[buf] + tid * 16);
    gload16(kbase + (size_t)t * 8192 + 4096 + tid * 16, ldsK[buf] + 4096 + tid * 16);
  };

  bf16x8 qf[4];
#pragma unroll
  for (int s = 0; s < 4; ++s)
    qf[s] = *(const bf16x8*)(q + (size_t)qrow * 768 + h * 64 + 16 * s + 8 * l5);

  stageK(0, 0);
  stageK(1, 1);

  f32x16 accO[2] = {};
  float mrow = -1e30f, lrow = 0.f;

  asm volatile("s_waitcnt vmcnt(0)" ::: "memory");
  __builtin_amdgcn_s_barrier();

  for (int t = 0; t < 16; ++t) {
    const char* bufK = ldsK[t % 3];

    bf16x8 vf[2][2][2];
    {
      const __bf16* vt = vbase + (size_t)(2 * t) * 2048 + vchunk;
#pragma unroll
      for (int nt = 0; nt < 2; ++nt)
#pragma unroll
        for (int dt = 0; dt < 2; ++dt)
#pragma unroll
          for (int ks = 0; ks < 2; ++ks)
            vf[nt][dt][ks] = *(const bf16x8*)(vt + nt * 2048 + (dt * 2 + ks) * 512);
    }
    if (t < 14) stageK(t + 2, (t + 2) % 3);

    f32x16 s16[2] = {};
    __builtin_amdgcn_s_setprio(1);
#pragma unroll
    for (int s = 0; s < 4; ++s) {
      bf16x8 kf0 = *(const bf16x8*)(bufK + (s * 2 + l5) * 512 + l32 * 16);
      s16[0] = __builtin_amdgcn_mfma_f32_32x32x16_bf16(kf0, qf[s], s16[0], 0, 0, 0);
      bf16x8 kf1 = *(const bf16x8*)(bufK + 4096 + (s * 2 + l5) * 512 + l32 * 16);
      s16[1] = __builtin_amdgcn_mfma_f32_32x32x16_bf16(kf1, qf[s], s16[1], 0, 0, 0);
    }
    __builtin_amdgcn_s_setprio(0);

    float lm = s16[0][0];
#pragma unroll
    for (int nt = 0; nt < 2; ++nt)
#pragma unroll
      for (int i = 0; i < 16; ++i) lm = fmaxf(lm, s16[nt][i]);
    if (!__all(lm <= mrow + 8.0f)) {
      float mx = fmaxf(lm, __shfl_xor(lm, 32, 64));
      float mn = fmaxf(mrow, mx);
      float corr = exp2_fast(mrow - mn);
      mrow = mn;
      lrow *= corr;
#pragma unroll
      for (int dt = 0; dt < 2; ++dt)
#pragma unroll
        for (int i = 0; i < 16; ++i) accO[dt][i] *= corr;
    }
    float ps = 0.f;
#pragma unroll
    for (int nt = 0; nt < 2; ++nt)
#pragma unroll
      for (int i = 0; i < 16; ++i) {
        float e = exp2_fast(s16[nt][i] - mrow);
        s16[nt][i] = e;
        ps += e;
      }
    lrow += ps;

    bf16x8 pk[2][2];
#pragma unroll
    for (int nt = 0; nt < 2; ++nt) {
      uint32_t c0[4], c1[4];
#pragma unroll
      for (int j = 0; j < 4; ++j) {
        c0[j] = cvtpk(s16[nt][4 * j], s16[nt][4 * j + 1]);
        c1[j] = cvtpk(s16[nt][4 * j + 2], s16[nt][4 * j + 3]);
      }
      uint32_t w00 = c0[0], w02 = c0[1];
      asm("v_permlane32_swap_b32 %0, %1" : "+v"(w00), "+v"(w02));
      uint32_t w01 = c1[0], w03 = c1[1];
      asm("v_permlane32_swap_b32 %0, %1" : "+v"(w01), "+v"(w03));
      uint32_t w10 = c0[2], w12 = c0[3];
      asm("v_permlane32_swap_b32 %0, %1" : "+v"(w10), "+v"(w12));
      uint32_t w11 = c1[2], w13 = c1[3];
      asm("v_permlane32_swap_b32 %0, %1" : "+v"(w11), "+v"(w13));
      union { uint32_t u[4]; bf16x8 v; } pk0, pk1;
      pk0.u[0] = w00; pk0.u[1] = w01; pk0.u[2] = w02; pk0.u[3] = w03;
      pk1.u[0] = w10; pk1.u[1] = w11; pk1.u[2] = w12; pk1.u[3] = w13;
      pk[nt][0] = pk0.v;
      pk[nt][1] = pk1.v;
    }

    __builtin_amdgcn_s_setprio(1);
#pragma unroll
    for (int nt = 0; nt < 2; ++nt)
#pragma unroll
      for (int ks = 0; ks < 2; ++ks) {
        accO[0] = __builtin_amdgcn_mfma_f32_32x32x16_bf16(vf[nt][0][ks], pk[nt][ks], accO[0], 0, 0, 0);
        accO[1] = __builtin_amdgcn_mfma_f32_32x32x16_bf16(vf[nt][1][ks], pk[nt][ks], accO[1], 0, 0, 0);
      }
    __builtin_amdgcn_s_setprio(0);

    __builtin_amdgcn_sched_barrier(0);
    __builtin_amdgcn_s_barrier();
  }

  float l = lrow + __shfl_xor(lrow, 32, 64);
  float inv = 1.0f / l;
  size_t rowb = (size_t)qrow * 768 + h * 64;
#pragma unroll
  for (int dt = 0; dt < 2; ++dt)
#pragma unroll
    for (int j = 0; j < 4; ++j) {
      bf16x4 o;
#pragma unroll
      for (int i = 0; i < 4; ++i) o[i] = (__bf16)(accO[dt][4 * j + i] * inv);
      *(bf16x4*)(ao + rowb + dt * 32 + 8 * j + 4 * l5) = o;
    }
}

extern "C" void kernel_launch(void* const* d_in, const int* in_sizes, int n_in,
                              void* d_out, int out_size, void* d_ws, size_t ws_size,
                              hipStream_t stream) {
  const float* x = (const float*)d_in[0];
  const float* r = (const float*)d_in[1];
  const float* Wq = (const float*)d_in[2];
  const float* Wkv = (const float*)d_in[3];
  const float* Wp = (const float*)d_in[4];
  const float* bp = (const float*)d_in[5];

  char* ws = (char*)d_ws;
  __bf16* xb  = (__bf16*)ws; ws += (size_t)6291456 * 2;  // x bf16 (8192x768)
  __bf16* rb  = (__bf16*)ws; ws += (size_t)3145728 * 2;  // r bf16 (4096x768)
  __bf16* wqt = (__bf16*)ws; ws += (size_t)589824 * 2;   // W_q^T * SCALE*log2e
  __bf16* wkvt= (__bf16*)ws; ws += (size_t)1179648 * 2;  // W_kv^T (1536x768)
  __bf16* wpt = (__bf16*)ws; ws += (size_t)589824 * 2;   // W_proj^T (768x768)
  __bf16* qb  = (__bf16*)ws; ws += (size_t)6291456 * 2;  // q (8192x768), pre-scaled
  __bf16* kbk = (__bf16*)ws; ws += (size_t)3145728 * 2;  // K blocked (48 bh x 32 t x 4KB)
  __bf16* vbk = (__bf16*)ws; ws += (size_t)3145728 * 2;  // V blocked (48 bh x 32 t x 4KB)
  __bf16* ao  = (__bf16*)ws;                              // attn out (8192x768)

  k_cast2<<<9216, 256, 0, stream>>>(x, r, xb, rb);
  k_twc3<<<dim3(48, 24, 3), 256, 0, stream>>>(Wq, Wkv, Wp, wqt, wkvt, wpt);
  k_gemm12<<<768, 256, 0, stream>>>(xb, rb, wqt, wkvt, qb, kbk, vbk);
  k_attn<<<dim3(16, 48), 256, 0, stream>>>(qb, kbk, vbk, ao);
  k_gemmP<<<dim3(6, 64), 256, 0, stream>>>(ao, wpt, (float*)d_out, bp);
}